// Round 6
// baseline (158.843 us; speedup 1.0000x reference)
//
#include <hip/hip_runtime.h>
#include <math.h>

#define BB 32
#define NN 4096
#define DD 512
#define CC 5
#define SSEG 16   // 32*16 = 512 blocks = exactly 2 resident blocks/CU; 64 rows/wave = 16 batches of 4

// DPP-add step: v += dpp_permuted(v). bound_ctrl=1 -> 0 for lanes w/o source.
#define DPP_ADD(v, ctrl, rmask)                                                 \
    (v) += __int_as_float(__builtin_amdgcn_update_dpp(                          \
        0, __float_as_int(v), (ctrl), (rmask), 0xF, true))

// Canonical CDNA wave64 all-reduce via DPP only (no DS pipe), result made
// wave-uniform via readlane 63.
static __device__ __forceinline__ float wave_allreduce_add(float v)
{
    DPP_ADD(v, 0x111, 0xF);   // row_shr:1
    DPP_ADD(v, 0x112, 0xF);   // row_shr:2
    DPP_ADD(v, 0x114, 0xF);   // row_shr:4
    DPP_ADD(v, 0x118, 0xF);   // row_shr:8
    DPP_ADD(v, 0x142, 0xA);   // row_bcast:15 -> rows 1,3
    DPP_ADD(v, 0x143, 0xC);   // row_bcast:31 -> rows 2,3
    return __int_as_float(__builtin_amdgcn_readlane(__float_as_int(v), 63));
}

static __device__ __forceinline__ void load_batch4(const float* __restrict__ xbase,
                                                   int row, int d0, int d1,
                                                   float4 xa[4], float4 xb[4])
{
#pragma unroll
    for (int r = 0; r < 4; ++r) {
        const float* xr = xbase + (size_t)(row + r) * DD;
        xa[r] = *reinterpret_cast<const float4*>(xr + d0);
        xb[r] = *reinterpret_cast<const float4*>(xr + d1);
    }
}

static __device__ __forceinline__ void process_batch4(const float4 xa[4], const float4 xb[4],
                                                      const float wal[20], const float wah[20],
                                                      float acc[CC][8], float m[CC], float l[CC])
{
    // e partials: 20 independent dots
    float e[4][CC];
#pragma unroll
    for (int r = 0; r < 4; ++r) {
        const float xv[8] = {xa[r].x, xa[r].y, xa[r].z, xa[r].w,
                             xb[r].x, xb[r].y, xb[r].z, xb[r].w};
#pragma unroll
        for (int c = 0; c < CC; ++c) {
            float s = 0.0f;
#pragma unroll
            for (int j = 0; j < 4; ++j) s = fmaf(xv[j], wal[j * CC + c], s);
#pragma unroll
            for (int j = 0; j < 4; ++j) s = fmaf(xv[4 + j], wah[j * CC + c], s);
            e[r][c] = s;
        }
    }
    // 20 interleaved DPP reduce chains -> wave-uniform e
#pragma unroll
    for (int r = 0; r < 4; ++r)
#pragma unroll
        for (int c = 0; c < CC; ++c)
            e[r][c] = wave_allreduce_add(e[r][c]);

    // batch max + single amortized rescale
    float mb[CC];
#pragma unroll
    for (int c = 0; c < CC; ++c)
        mb[c] = fmaxf(fmaxf(e[0][c], e[1][c]), fmaxf(e[2][c], e[3][c]));

    bool raise = false;
#pragma unroll
    for (int c = 0; c < CC; ++c) raise = raise || (mb[c] > m[c]);

    if (__ballot(raise) != 0ull) {   // wave-uniform branch
#pragma unroll
        for (int c = 0; c < CC; ++c) {
            const float mn = fmaxf(m[c], mb[c]);
            const float sc = __expf(m[c] - mn);   // 0 when m == -inf
            l[c] *= sc;
#pragma unroll
            for (int j = 0; j < 8; ++j) acc[c][j] *= sc;
            m[c] = mn;
        }
    }

    // weighted accumulation
#pragma unroll
    for (int r = 0; r < 4; ++r) {
        const float xv[8] = {xa[r].x, xa[r].y, xa[r].z, xa[r].w,
                             xb[r].x, xb[r].y, xb[r].z, xb[r].w};
#pragma unroll
        for (int c = 0; c < CC; ++c) {
            const float p = __expf(e[r][c] - m[c]);
            l[c] += p;
#pragma unroll
            for (int j = 0; j < 8; ++j) acc[c][j] = fmaf(p, xv[j], acc[c][j]);
        }
    }
}

// Fused kernel: streams x once (ping-pong prefetched 4-row batches), writes
// per-(b,seg) partials, then the LAST block to finish each b runs the
// cross-segment combine + epilogue (split-k fixup pattern).
__global__ __launch_bounds__(256, 2)
void capsule_fused(const float* __restrict__ x, const float* __restrict__ Wa,
                   const float* __restrict__ lin_w, const float* __restrict__ lin_b,
                   float* __restrict__ acc_ws, float* __restrict__ ml_ws,
                   int* __restrict__ cnt,
                   float* __restrict__ p_out, float* __restrict__ v_out,
                   float* __restrict__ r_out)
{
    const int blk  = blockIdx.x;
    const int b    = blk / SSEG;
    const int seg  = blk % SSEG;
    const int tid  = threadIdx.x;
    const int lane = tid & 63;
    const int wid  = tid >> 6;   // 0..3

    const int d0 = lane * 4;
    const int d1 = 256 + lane * 4;

    // W_alpha fragments (4 d's x 5 c's per half), float4 loads
    float wal[20], wah[20];
    {
        const float4* pl = reinterpret_cast<const float4*>(Wa + d0 * CC);
        const float4* ph = reinterpret_cast<const float4*>(Wa + d1 * CC);
#pragma unroll
        for (int q = 0; q < 5; ++q) {
            float4 a = pl[q];
            wal[q * 4 + 0] = a.x; wal[q * 4 + 1] = a.y;
            wal[q * 4 + 2] = a.z; wal[q * 4 + 3] = a.w;
            float4 b4 = ph[q];
            wah[q * 4 + 0] = b4.x; wah[q * 4 + 1] = b4.y;
            wah[q * 4 + 2] = b4.z; wah[q * 4 + 3] = b4.w;
        }
    }

    float acc[CC][8];
    float m[CC], l[CC];
#pragma unroll
    for (int c = 0; c < CC; ++c) {
        m[c] = -INFINITY;
        l[c] = 0.0f;
#pragma unroll
        for (int j = 0; j < 8; ++j) acc[c][j] = 0.0f;
    }

    // segment = 256 rows; wave slice = 64 rows = 16 batches of 4 (exact)
    const int rs  = seg * (NN / SSEG);
    const int ws_ = rs + wid * (NN / SSEG / 4);
    const int we_ = ws_ + (NN / SSEG / 4);

    const float* xb_ = x + (size_t)b * NN * DD;

    // ping-pong double buffer: loads for batch k+1 issue before compute of k
    float4 xaA[4], xbA[4], xaB[4], xbB[4];
    load_batch4(xb_, ws_, d0, d1, xaA, xbA);
    for (int i0 = ws_; i0 < we_; i0 += 8) {
        load_batch4(xb_, i0 + 4, d0, d1, xaB, xbB);
        process_batch4(xaA, xbA, wal, wah, acc, m, l);
        const int nxt = (i0 + 8 < we_) ? (i0 + 8) : i0;   // clamped dead prefetch on last iter
        load_batch4(xb_, nxt, d0, d1, xaA, xbA);
        process_batch4(xaB, xbB, wal, wah, acc, m, l);
    }

    // ---- combine the 4 waves ----
    __shared__ float s_ml[4][CC][2];
    __shared__ float s_acc[CC][DD];   // 10 KB
    __shared__ float s_red[4];
    __shared__ int   s_last;

    if (lane == 0) {
#pragma unroll
        for (int c = 0; c < CC; ++c) {
            s_ml[wid][c][0] = m[c];
            s_ml[wid][c][1] = l[c];
        }
    }
    __syncthreads();

    float mb2[CC], lb2[CC], cw[CC];
#pragma unroll
    for (int c = 0; c < CC; ++c) {
        float mm = s_ml[0][c][0];
#pragma unroll
        for (int w = 1; w < 4; ++w) mm = fmaxf(mm, s_ml[w][c][0]);
        mb2[c] = mm;
        float ll = 0.0f;
#pragma unroll
        for (int w = 0; w < 4; ++w) ll += __expf(s_ml[w][c][0] - mm) * s_ml[w][c][1];
        lb2[c] = ll;
        cw[c] = __expf(s_ml[wid][c][0] - mm);
    }

    for (int w = 0; w < 4; ++w) {
        if (wid == w) {
#pragma unroll
            for (int c = 0; c < CC; ++c) {
#pragma unroll
                for (int j = 0; j < 8; ++j) {
                    const int d = (j < 4) ? (d0 + j) : (d1 + j - 4);
                    const float v = acc[c][j] * cw[c];
                    if (w == 0) s_acc[c][d] = v;
                    else        s_acc[c][d] += v;
                }
            }
        }
        __syncthreads();
    }

    // write block partials to workspace (float4)
    float4* accp = reinterpret_cast<float4*>(acc_ws + (size_t)blk * CC * DD);
    const float4* sa = reinterpret_cast<const float4*>(&s_acc[0][0]);
    for (int idx = tid; idx < CC * DD / 4; idx += 256) accp[idx] = sa[idx];
    if (tid < CC) {
        ml_ws[((size_t)blk * CC + tid) * 2 + 0] = mb2[tid];
        ml_ws[((size_t)blk * CC + tid) * 2 + 1] = lb2[tid];
    }

    // ---- last-block-per-b finisher (split-k fixup) ----
    __threadfence();                      // release: flush partials device-wide
    __syncthreads();                      // all ws writes of this block issued
    if (tid == 0) s_last = (atomicAdd(&cnt[b], 1) == SSEG - 1) ? 1 : 0;
    __syncthreads();
    if (!s_last) return;
    __threadfence();                      // acquire: invalidate stale lines

    float wseg[SSEG];
    for (int c = 0; c < CC; ++c) {
        float mg = -INFINITY;
        for (int s = 0; s < SSEG; ++s)
            mg = fmaxf(mg, ml_ws[(((size_t)b * SSEG + s) * CC + c) * 2]);
        float lg = 0.0f;
        for (int s = 0; s < SSEG; ++s) {
            const float mw = ml_ws[(((size_t)b * SSEG + s) * CC + c) * 2];
            const float lw = ml_ws[(((size_t)b * SSEG + s) * CC + c) * 2 + 1];
            wseg[s] = __expf(mw - mg);
            lg += wseg[s] * lw;
        }
        const float inv_l = 1.0f / lg;

        float v0 = 0.0f, v1 = 0.0f;
        for (int s = 0; s < SSEG; ++s) {
            const float* ap = acc_ws + (((size_t)b * SSEG + s) * CC + c) * DD;
            v0 = fmaf(wseg[s], ap[tid], v0);
            v1 = fmaf(wseg[s], ap[tid + 256], v1);
        }
        v0 *= inv_l;
        v1 *= inv_l;

        const int bc = b * CC + c;
        v_out[(size_t)bc * DD + tid]       = v0;
        v_out[(size_t)bc * DD + tid + 256] = v1;

        float part = v0 * lin_w[tid] + v1 * lin_w[tid + 256];
#pragma unroll
        for (int off = 1; off < 64; off <<= 1) part += __shfl_xor(part, off, 64);
        if ((tid & 63) == 0) s_red[tid >> 6] = part;
        __syncthreads();
        const float p = tanhf(s_red[0] + s_red[1] + s_red[2] + s_red[3] + lin_b[0]);
        if (tid == 0) p_out[bc] = p;
        r_out[(size_t)bc * DD + tid]       = p * v0;
        r_out[(size_t)bc * DD + tid + 256] = p * v1;
        __syncthreads();   // s_red reused next c
    }
}

extern "C" void kernel_launch(void* const* d_in, const int* in_sizes, int n_in,
                              void* d_out, int out_size, void* d_ws, size_t ws_size,
                              hipStream_t stream) {
    const float* x   = (const float*)d_in[0];
    const float* Wa  = (const float*)d_in[1];
    const float* lw  = (const float*)d_in[2];
    const float* lb  = (const float*)d_in[3];

    float* out   = (float*)d_out;
    float* p_out = out;                       // (B, C)
    float* v_out = out + BB * CC;             // (B, C, D)
    float* r_out = v_out + BB * CC * DD;      // (B, C, D)

    float* acc_ws = (float*)d_ws;                           // B*SSEG*C*D floats
    float* ml_ws  = acc_ws + (size_t)BB * SSEG * CC * DD;   // B*SSEG*C*2 floats
    int*   cnt    = (int*)(ml_ws + (size_t)BB * SSEG * CC * 2);  // B ints

    hipMemsetAsync(cnt, 0, BB * sizeof(int), stream);

    capsule_fused<<<dim3(BB * SSEG), dim3(256), 0, stream>>>(
        x, Wa, lw, lb, acc_ws, ml_ws, cnt, p_out, v_out, r_out);
}

// Round 7
// 57.795 us; speedup vs baseline: 2.7484x; 2.7484x over previous
//
#include <hip/hip_runtime.h>
#include <math.h>

#define BB 32
#define NN 4096
#define DD 512
#define CC 5
#define SSEG 16   // 32*16 = 512 blocks = exactly 2 resident blocks/CU (launch_bounds 256,2)

// DPP-add step: v += dpp_permuted(v). bound_ctrl=1 -> 0 for lanes w/o source.
#define DPP_ADD(v, ctrl, rmask)                                                 \
    (v) += __int_as_float(__builtin_amdgcn_update_dpp(                          \
        0, __float_as_int(v), (ctrl), (rmask), 0xF, true))

// Canonical CDNA wave64 all-reduce via DPP only (no DS pipe), result made
// wave-uniform via readlane 63.
static __device__ __forceinline__ float wave_allreduce_add(float v)
{
    DPP_ADD(v, 0x111, 0xF);   // row_shr:1
    DPP_ADD(v, 0x112, 0xF);   // row_shr:2
    DPP_ADD(v, 0x114, 0xF);   // row_shr:4
    DPP_ADD(v, 0x118, 0xF);   // row_shr:8
    DPP_ADD(v, 0x142, 0xA);   // row_bcast:15 -> rows 1,3
    DPP_ADD(v, 0x143, 0xC);   // row_bcast:31 -> rows 2,3
    return __int_as_float(__builtin_amdgcn_readlane(__float_as_int(v), 63));
}

// All hot-loop bodies are macros over kernel-scope arrays with fully unrolled
// compile-time indices -> everything stays in VGPRs (R6 lesson: passing these
// arrays to functions took their address and spilled them to scratch).
#define LOADB(XA, XB, row)                                                      \
    {                                                                           \
        _Pragma("unroll")                                                       \
        for (int _r = 0; _r < 4; ++_r) {                                        \
            const float* _xr = xb_ + (size_t)((row) + _r) * DD;                 \
            XA[_r] = *reinterpret_cast<const float4*>(_xr + d0);                \
            XB[_r] = *reinterpret_cast<const float4*>(_xr + d1);                \
        }                                                                       \
    }

#define PROCB(XA, XB)                                                           \
    {                                                                           \
        float _e[4][CC];                                                        \
        _Pragma("unroll")                                                       \
        for (int _r = 0; _r < 4; ++_r) {                                        \
            const float _xv[8] = {XA[_r].x, XA[_r].y, XA[_r].z, XA[_r].w,       \
                                  XB[_r].x, XB[_r].y, XB[_r].z, XB[_r].w};      \
            _Pragma("unroll")                                                   \
            for (int _c = 0; _c < CC; ++_c) {                                   \
                float _s = 0.0f;                                                \
                _Pragma("unroll")                                               \
                for (int _j = 0; _j < 4; ++_j)                                  \
                    _s = fmaf(_xv[_j], wal[_j * CC + _c], _s);                  \
                _Pragma("unroll")                                               \
                for (int _j = 0; _j < 4; ++_j)                                  \
                    _s = fmaf(_xv[4 + _j], wah[_j * CC + _c], _s);              \
                _e[_r][_c] = _s;                                                \
            }                                                                   \
        }                                                                       \
        _Pragma("unroll")                                                       \
        for (int _r = 0; _r < 4; ++_r)                                          \
            _Pragma("unroll")                                                   \
            for (int _c = 0; _c < CC; ++_c)                                     \
                _e[_r][_c] = wave_allreduce_add(_e[_r][_c]);                    \
        float _mb[CC];                                                          \
        _Pragma("unroll")                                                       \
        for (int _c = 0; _c < CC; ++_c)                                         \
            _mb[_c] = fmaxf(fmaxf(_e[0][_c], _e[1][_c]),                        \
                            fmaxf(_e[2][_c], _e[3][_c]));                       \
        bool _raise = false;                                                    \
        _Pragma("unroll")                                                       \
        for (int _c = 0; _c < CC; ++_c) _raise = _raise || (_mb[_c] > m[_c]);   \
        if (__ballot(_raise) != 0ull) {                                         \
            _Pragma("unroll")                                                   \
            for (int _c = 0; _c < CC; ++_c) {                                   \
                const float _mn = fmaxf(m[_c], _mb[_c]);                        \
                const float _sc = __expf(m[_c] - _mn);                          \
                l[_c] *= _sc;                                                   \
                _Pragma("unroll")                                               \
                for (int _j = 0; _j < 8; ++_j) acc[_c][_j] *= _sc;              \
                m[_c] = _mn;                                                    \
            }                                                                   \
        }                                                                       \
        _Pragma("unroll")                                                       \
        for (int _r = 0; _r < 4; ++_r) {                                        \
            const float _xv[8] = {XA[_r].x, XA[_r].y, XA[_r].z, XA[_r].w,       \
                                  XB[_r].x, XB[_r].y, XB[_r].z, XB[_r].w};      \
            _Pragma("unroll")                                                   \
            for (int _c = 0; _c < CC; ++_c) {                                   \
                const float _p = __expf(_e[_r][_c] - m[_c]);                    \
                l[_c] += _p;                                                    \
                _Pragma("unroll")                                               \
                for (int _j = 0; _j < 8; ++_j)                                  \
                    acc[_c][_j] = fmaf(_p, _xv[_j], acc[_c][_j]);               \
            }                                                                   \
        }                                                                       \
    }

// Pass 1: stream x once. Block = (b, segment of 256 rows). 4 waves; each wave
// owns 64 contiguous rows = 16 batches of 4, processed with a full ping-pong
// register double-buffer so ~8 KB/wave stays outstanding continuously.
__global__ __launch_bounds__(256, 2)
void capsule_pass1(const float* __restrict__ x, const float* __restrict__ Wa,
                   float* __restrict__ acc_ws, float* __restrict__ ml_ws)
{
    const int blk  = blockIdx.x;
    const int b    = blk / SSEG;
    const int seg  = blk % SSEG;
    const int tid  = threadIdx.x;
    const int lane = tid & 63;
    const int wid  = tid >> 6;   // 0..3

    const int d0 = lane * 4;
    const int d1 = 256 + lane * 4;

    // W_alpha fragments (4 d's x 5 c's per half), float4 loads
    float wal[20], wah[20];
    {
        const float4* pl = reinterpret_cast<const float4*>(Wa + d0 * CC);
        const float4* ph = reinterpret_cast<const float4*>(Wa + d1 * CC);
#pragma unroll
        for (int q = 0; q < 5; ++q) {
            float4 a = pl[q];
            wal[q * 4 + 0] = a.x; wal[q * 4 + 1] = a.y;
            wal[q * 4 + 2] = a.z; wal[q * 4 + 3] = a.w;
            float4 b4 = ph[q];
            wah[q * 4 + 0] = b4.x; wah[q * 4 + 1] = b4.y;
            wah[q * 4 + 2] = b4.z; wah[q * 4 + 3] = b4.w;
        }
    }

    float acc[CC][8];
    float m[CC], l[CC];
#pragma unroll
    for (int c = 0; c < CC; ++c) {
        m[c] = -INFINITY;
        l[c] = 0.0f;
#pragma unroll
        for (int j = 0; j < 8; ++j) acc[c][j] = 0.0f;
    }

    // segment = 256 rows; wave slice = 64 rows = 16 batches of 4 (exact)
    const int rs  = seg * (NN / SSEG);
    const int ws_ = rs + wid * (NN / SSEG / 4);
    const int we_ = ws_ + (NN / SSEG / 4);

    const float* xb_ = x + (size_t)b * NN * DD;

    float4 xaA[4], xbA[4], xaB[4], xbB[4];
    LOADB(xaA, xbA, ws_);
    for (int i0 = ws_; i0 < we_; i0 += 8) {
        LOADB(xaB, xbB, i0 + 4);
        PROCB(xaA, xbA);
        const int nxt = (i0 + 8 < we_) ? (i0 + 8) : i0;   // clamped (dead) on last iter
        LOADB(xaA, xbA, nxt);
        PROCB(xaB, xbB);
    }

    // ---- combine the 4 waves ----
    __shared__ float s_ml[4][CC][2];
    __shared__ float s_acc[CC][DD];   // 10 KB

    if (lane == 0) {
#pragma unroll
        for (int c = 0; c < CC; ++c) {
            s_ml[wid][c][0] = m[c];
            s_ml[wid][c][1] = l[c];
        }
    }
    __syncthreads();

    float mb2[CC], lb2[CC], cw[CC];
#pragma unroll
    for (int c = 0; c < CC; ++c) {
        float mm = s_ml[0][c][0];
#pragma unroll
        for (int w = 1; w < 4; ++w) mm = fmaxf(mm, s_ml[w][c][0]);
        mb2[c] = mm;
        float ll = 0.0f;
#pragma unroll
        for (int w = 0; w < 4; ++w) ll += __expf(s_ml[w][c][0] - mm) * s_ml[w][c][1];
        lb2[c] = ll;
        cw[c] = __expf(s_ml[wid][c][0] - mm);
    }

    for (int w = 0; w < 4; ++w) {
        if (wid == w) {
#pragma unroll
            for (int c = 0; c < CC; ++c) {
#pragma unroll
                for (int j = 0; j < 8; ++j) {
                    const int d = (j < 4) ? (d0 + j) : (d1 + j - 4);
                    const float v = acc[c][j] * cw[c];
                    if (w == 0) s_acc[c][d] = v;
                    else        s_acc[c][d] += v;
                }
            }
        }
        __syncthreads();
    }

    // write block partials to workspace (float4)
    float4* accp = reinterpret_cast<float4*>(acc_ws + (size_t)blk * CC * DD);
    const float4* sa = reinterpret_cast<const float4*>(&s_acc[0][0]);
    for (int idx = tid; idx < CC * DD / 4; idx += 256) accp[idx] = sa[idx];
    if (tid < CC) {
        ml_ws[((size_t)blk * CC + tid) * 2 + 0] = mb2[tid];
        ml_ws[((size_t)blk * CC + tid) * 2 + 1] = lb2[tid];
    }
}

// Pass 2: one block per (b,c). Combine SSEG segment partials, normalize,
// epilogue p = tanh(v.w + b), r = p*v, write all three outputs.
__global__ __launch_bounds__(256)
void capsule_pass2(const float* __restrict__ acc_ws, const float* __restrict__ ml_ws,
                   const float* __restrict__ lin_w, const float* __restrict__ lin_b,
                   float* __restrict__ p_out, float* __restrict__ v_out,
                   float* __restrict__ r_out)
{
    const int bc  = blockIdx.x;          // 0..B*C-1
    const int b   = bc / CC;
    const int c   = bc % CC;
    const int tid = threadIdx.x;

    __shared__ float s_w[SSEG];
    __shared__ float s_red[4];
    __shared__ float s_p;

    float mg = -INFINITY;
    for (int s = 0; s < SSEG; ++s)
        mg = fmaxf(mg, ml_ws[(((size_t)b * SSEG + s) * CC + c) * 2]);
    float lg = 0.0f;
    for (int s = 0; s < SSEG; ++s) {
        const float mw = ml_ws[(((size_t)b * SSEG + s) * CC + c) * 2];
        const float lw = ml_ws[(((size_t)b * SSEG + s) * CC + c) * 2 + 1];
        const float w  = __expf(mw - mg);
        lg += w * lw;
        if (tid == 0) s_w[s] = w;
    }
    __syncthreads();

    const float inv_l = 1.0f / lg;
    float v0 = 0.0f, v1 = 0.0f;
    for (int s = 0; s < SSEG; ++s) {
        const float* ap = acc_ws + (((size_t)b * SSEG + s) * CC + c) * DD;
        const float w = s_w[s];
        v0 = fmaf(w, ap[tid], v0);
        v1 = fmaf(w, ap[tid + 256], v1);
    }
    v0 *= inv_l;
    v1 *= inv_l;

    v_out[(size_t)bc * DD + tid]       = v0;
    v_out[(size_t)bc * DD + tid + 256] = v1;

    float part = v0 * lin_w[tid] + v1 * lin_w[tid + 256];
#pragma unroll
    for (int off = 1; off < 64; off <<= 1) part += __shfl_xor(part, off, 64);
    if ((tid & 63) == 0) s_red[tid >> 6] = part;
    __syncthreads();
    if (tid == 0) {
        const float dot = s_red[0] + s_red[1] + s_red[2] + s_red[3] + lin_b[0];
        const float p = tanhf(dot);
        s_p = p;
        p_out[bc] = p;
    }
    __syncthreads();
    const float p = s_p;
    r_out[(size_t)bc * DD + tid]       = p * v0;
    r_out[(size_t)bc * DD + tid + 256] = p * v1;
}

extern "C" void kernel_launch(void* const* d_in, const int* in_sizes, int n_in,
                              void* d_out, int out_size, void* d_ws, size_t ws_size,
                              hipStream_t stream) {
    const float* x   = (const float*)d_in[0];
    const float* Wa  = (const float*)d_in[1];
    const float* lw  = (const float*)d_in[2];
    const float* lb  = (const float*)d_in[3];

    float* out   = (float*)d_out;
    float* p_out = out;                       // (B, C)
    float* v_out = out + BB * CC;             // (B, C, D)
    float* r_out = v_out + BB * CC * DD;      // (B, C, D)

    float* acc_ws = (float*)d_ws;                           // B*SSEG*C*D floats
    float* ml_ws  = acc_ws + (size_t)BB * SSEG * CC * DD;   // B*SSEG*C*2 floats

    capsule_pass1<<<dim3(BB * SSEG), dim3(256), 0, stream>>>(x, Wa, acc_ws, ml_ws);
    capsule_pass2<<<dim3(BB * CC), dim3(256), 0, stream>>>(acc_ws, ml_ws, lw, lb,
                                                           p_out, v_out, r_out);
}